// Round 1
// baseline (1378.164 us; speedup 1.0000x reference)
//
#include <hip/hip_runtime.h>
#include <hip/hip_bf16.h>
#include <math.h>

#define SEQ    2048
#define BATCH  2
#define DM     1024
#define NH     16
#define DH     64
#define BS_ROWS (BATCH*SEQ)       // 4096
#define QKV_ELEMS (BS_ROWS*DM)    // 4194304

__device__ __forceinline__ float rdl(float v, int l) {
  return __int_as_float(__builtin_amdgcn_readlane(__float_as_int(v), l));
}

// ---------------------------------------------------------------------------
// GEMM: C[z][4096,1024] = X[4096,1024] @ W[z][1024,1024], optional RoPE epilogue
// 128x128 tile, BK=16, 256 threads, 8x8 micro-tile.
// ---------------------------------------------------------------------------
__global__ __launch_bounds__(256)
void gemm_k(const float* __restrict__ X,
            const float* __restrict__ W0, const float* __restrict__ W1,
            const float* __restrict__ W2,
            float* __restrict__ C0, float* __restrict__ C1, float* __restrict__ C2,
            int rope_mask)
{
  const int z = blockIdx.z;
  const float* __restrict__ W = (z == 0) ? W0 : ((z == 1) ? W1 : W2);
  float* __restrict__ C = (z == 0) ? C0 : ((z == 1) ? C1 : C2);
  const bool do_rope = ((rope_mask >> z) & 1) != 0;

  __shared__ float As[16][132];   // [k][m], padded
  __shared__ float Bs[16][132];   // [k][n], padded

  const int t  = threadIdx.x;
  const int tx = t & 15;
  const int ty = t >> 4;
  const int row0 = blockIdx.y * 128;
  const int col0 = blockIdx.x * 128;

  const int ar = t >> 2;          // 0..63
  const int ak = (t & 3) << 2;    // 0,4,8,12
  const int bk = t >> 4;          // 0..15
  const int bc = (t & 15) << 2;   // 0..60

  float acc[8][8];
  #pragma unroll
  for (int i = 0; i < 8; i++)
    #pragma unroll
    for (int j = 0; j < 8; j++) acc[i][j] = 0.0f;

  for (int k0 = 0; k0 < DM; k0 += 16) {
    float4 a0 = *(const float4*)&X[(row0 + ar) * DM + k0 + ak];
    float4 a1 = *(const float4*)&X[(row0 + ar + 64) * DM + k0 + ak];
    float4 b0 = *(const float4*)&W[(k0 + bk) * DM + col0 + bc];
    float4 b1 = *(const float4*)&W[(k0 + bk) * DM + col0 + bc + 64];
    As[ak + 0][ar] = a0.x; As[ak + 1][ar] = a0.y;
    As[ak + 2][ar] = a0.z; As[ak + 3][ar] = a0.w;
    As[ak + 0][ar + 64] = a1.x; As[ak + 1][ar + 64] = a1.y;
    As[ak + 2][ar + 64] = a1.z; As[ak + 3][ar + 64] = a1.w;
    *(float4*)&Bs[bk][bc]      = b0;
    *(float4*)&Bs[bk][bc + 64] = b1;
    __syncthreads();
    #pragma unroll
    for (int kk = 0; kk < 16; kk++) {
      const float4 A0 = *(const float4*)&As[kk][8 * ty];
      const float4 A1 = *(const float4*)&As[kk][8 * ty + 4];
      const float4 B0 = *(const float4*)&Bs[kk][8 * tx];
      const float4 B1 = *(const float4*)&Bs[kk][8 * tx + 4];
      const float a[8]  = {A0.x, A0.y, A0.z, A0.w, A1.x, A1.y, A1.z, A1.w};
      const float bb[8] = {B0.x, B0.y, B0.z, B0.w, B1.x, B1.y, B1.z, B1.w};
      #pragma unroll
      for (int i = 0; i < 8; i++)
        #pragma unroll
        for (int j = 0; j < 8; j++)
          acc[i][j] = fmaf(a[i], bb[j], acc[i][j]);
    }
    __syncthreads();
  }

  if (do_rope) {
    #pragma unroll
    for (int i = 0; i < 8; i++) {
      const int grow = row0 + 8 * ty + i;
      const float s = (float)(grow & (SEQ - 1));
      #pragma unroll
      for (int jp = 0; jp < 4; jp++) {
        const int col = col0 + 8 * tx + 2 * jp;
        const int p = (col & (DH - 1)) >> 1;
        // inv_freq = 10000^(-p/32) = 2^(-p * log2(10000)/32)
        const float freq = exp2f((float)p * -0.41524101186092030f);
        const float ang = s * freq;
        float sn, cs;
        sincosf(ang, &sn, &cs);
        const float e = acc[i][2 * jp], o = acc[i][2 * jp + 1];
        acc[i][2 * jp]     = e * cs - o * sn;
        acc[i][2 * jp + 1] = e * sn + o * cs;
      }
    }
  }

  #pragma unroll
  for (int i = 0; i < 8; i++) {
    const int grow = row0 + 8 * ty + i;
    float4 v0 = make_float4(acc[i][0], acc[i][1], acc[i][2], acc[i][3]);
    float4 v1 = make_float4(acc[i][4], acc[i][5], acc[i][6], acc[i][7]);
    *(float4*)&C[grow * DM + col0 + 8 * tx]     = v0;
    *(float4*)&C[grow * DM + col0 + 8 * tx + 4] = v1;
  }
}

// ---------------------------------------------------------------------------
// Flash attention, fp32, causal. 4 waves/block, 4 query rows per wave.
// Lane j loads K row (kbase+j); Q register-resident (lane = d), broadcast via
// readlane; online softmax with 64-lane shfl reductions; V read coalesced.
// ---------------------------------------------------------------------------
__global__ __launch_bounds__(256)
void attn_k(const float* __restrict__ Q, const float* __restrict__ K,
            const float* __restrict__ V, float* __restrict__ A)
{
  const int lane = threadIdx.x & 63;
  const int wave = threadIdx.x >> 6;
  const int bh = blockIdx.y;
  const int b = bh >> 4, h = bh & 15;
  const int r0 = blockIdx.x * 16 + wave * 4;

  const float* __restrict__ Qb = Q + (b * SEQ) * DM + h * DH;
  const float* __restrict__ Kb = K + (b * SEQ) * DM + h * DH;
  const float* __restrict__ Vb = V + (b * SEQ) * DM + h * DH;

  float qv[4];
  #pragma unroll
  for (int r = 0; r < 4; r++)
    qv[r] = Qb[(r0 + r) * DM + lane] * 0.03125f;   // fold 1/sqrt(1024)

  float m[4], l[4], o[4];
  #pragma unroll
  for (int r = 0; r < 4; r++) { m[r] = -INFINITY; l[r] = 0.0f; o[r] = 0.0f; }

  const int kmax = r0 + 3;
  const int ntiles = (kmax >> 6) + 1;

  for (int kt = 0; kt < ntiles; kt++) {
    const int kbase = kt << 6;
    // ---- scores: s[r][lane] = sum_d Q[r][d] * K[kbase+lane][d]
    float s[4] = {0.0f, 0.0f, 0.0f, 0.0f};
    const float* Kr = Kb + (kbase + lane) * DM;
    #pragma unroll
    for (int c = 0; c < 16; c++) {
      const float4 k4 = *(const float4*)&Kr[4 * c];
      #pragma unroll
      for (int r = 0; r < 4; r++) {
        s[r] = fmaf(rdl(qv[r], 4 * c + 0), k4.x, s[r]);
        s[r] = fmaf(rdl(qv[r], 4 * c + 1), k4.y, s[r]);
        s[r] = fmaf(rdl(qv[r], 4 * c + 2), k4.z, s[r]);
        s[r] = fmaf(rdl(qv[r], 4 * c + 3), k4.w, s[r]);
      }
    }
    // ---- online softmax
    const int kidx = kbase + lane;
    float p[4];
    #pragma unroll
    for (int r = 0; r < 4; r++) {
      const float sr = (kidx <= r0 + r) ? s[r] : -INFINITY;
      float tm = sr;
      #pragma unroll
      for (int off = 32; off > 0; off >>= 1)
        tm = fmaxf(tm, __shfl_xor(tm, off));
      const float nm = fmaxf(m[r], tm);
      const float corr = __expf(m[r] - nm);
      const float pr = __expf(sr - nm);
      float ts = pr;
      #pragma unroll
      for (int off = 32; off > 0; off >>= 1)
        ts += __shfl_xor(ts, off);
      l[r] = l[r] * corr + ts;
      o[r] = o[r] * corr;
      m[r] = nm;
      p[r] = pr;
    }
    // ---- O[d=lane] += sum_k p[k] * V[k][d]
    const float* Vr = Vb + kbase * DM + lane;
    #pragma unroll
    for (int k = 0; k < 64; k++) {
      const float vv = Vr[k * DM];
      #pragma unroll
      for (int r = 0; r < 4; r++)
        o[r] = fmaf(rdl(p[r], k), vv, o[r]);
    }
  }

  float* __restrict__ Ab = A + (b * SEQ) * DM + h * DH;
  #pragma unroll
  for (int r = 0; r < 4; r++)
    Ab[(r0 + r) * DM + lane] = o[r] / l[r];
}

// ---------------------------------------------------------------------------
extern "C" void kernel_launch(void* const* d_in, const int* in_sizes, int n_in,
                              void* d_out, int out_size, void* d_ws, size_t ws_size,
                              hipStream_t stream) {
  const float* x  = (const float*)d_in[0];
  const float* qw = (const float*)d_in[1];
  const float* kw = (const float*)d_in[2];
  const float* vw = (const float*)d_in[3];
  const float* ow = (const float*)d_in[4];
  float* out = (float*)d_out;

  float* Q = (float*)d_ws;
  float* K = Q + QKV_ELEMS;
  float* V = K + QKV_ELEMS;
  float* A = Q;   // attention output aliases Q (same rows read/written per wave)

  dim3 blk(256);
  dim3 g1(DM / 128, BS_ROWS / 128, 3);
  gemm_k<<<g1, blk, 0, stream>>>(x, qw, kw, vw, Q, K, V, 0x3);

  dim3 g2(SEQ / 16, BATCH * NH, 1);
  attn_k<<<g2, blk, 0, stream>>>(Q, K, V, A);

  dim3 g3(DM / 128, BS_ROWS / 128, 1);
  gemm_k<<<g3, blk, 0, stream>>>(A, ow, ow, ow, out, out, out, 0x0);
}

// Round 3
// 596.014 us; speedup vs baseline: 2.3123x; 2.3123x over previous
//
#include <hip/hip_runtime.h>
#include <hip/hip_bf16.h>
#include <math.h>

#define SEQ    2048
#define BATCH  2
#define DM     1024
#define NH     16
#define DH     64
#define BS_ROWS 4096

typedef __attribute__((ext_vector_type(8))) short short8v;
typedef __attribute__((ext_vector_type(4))) float f32x4;

__device__ __forceinline__ unsigned short f2bf(float f) {
  union { float f; unsigned u; } v; v.f = f;
  unsigned r = (v.u + 0x7FFF + ((v.u >> 16) & 1)) >> 16;
  return (unsigned short)r;
}
__device__ __forceinline__ float bf2f(unsigned short h) {
  union { unsigned u; float f; } v; v.u = ((unsigned)h) << 16;
  return v.f;
}

// ---------------------------------------------------------------------------
// fp32 GEMM: C[z][4096,1024] = X @ W[z]. z==2 (V) writes transposed bf16
// Vt[b*16+h][d][s] instead of fp32 C.
// ---------------------------------------------------------------------------
__global__ __launch_bounds__(256)
void gemm_k(const float* __restrict__ X,
            const float* __restrict__ W0, const float* __restrict__ W1,
            const float* __restrict__ W2,
            float* __restrict__ C0, float* __restrict__ C1,
            unsigned short* __restrict__ Vt)
{
  const int z = blockIdx.z;
  const float* __restrict__ W = (z == 0) ? W0 : ((z == 1) ? W1 : W2);
  float* __restrict__ C = (z == 0) ? C0 : C1;

  __shared__ float As[16][132];
  __shared__ float Bs[16][132];

  const int t  = threadIdx.x;
  const int tx = t & 15;
  const int ty = t >> 4;
  const int row0 = blockIdx.y * 128;
  const int col0 = blockIdx.x * 128;

  const int ar = t >> 2;
  const int ak = (t & 3) << 2;
  const int bk = t >> 4;
  const int bc = (t & 15) << 2;

  float acc[8][8];
  #pragma unroll
  for (int i = 0; i < 8; i++)
    #pragma unroll
    for (int j = 0; j < 8; j++) acc[i][j] = 0.0f;

  for (int k0 = 0; k0 < DM; k0 += 16) {
    float4 a0 = *(const float4*)&X[(row0 + ar) * DM + k0 + ak];
    float4 a1 = *(const float4*)&X[(row0 + ar + 64) * DM + k0 + ak];
    float4 b0 = *(const float4*)&W[(k0 + bk) * DM + col0 + bc];
    float4 b1 = *(const float4*)&W[(k0 + bk) * DM + col0 + bc + 64];
    As[ak + 0][ar] = a0.x; As[ak + 1][ar] = a0.y;
    As[ak + 2][ar] = a0.z; As[ak + 3][ar] = a0.w;
    As[ak + 0][ar + 64] = a1.x; As[ak + 1][ar + 64] = a1.y;
    As[ak + 2][ar + 64] = a1.z; As[ak + 3][ar + 64] = a1.w;
    *(float4*)&Bs[bk][bc]      = b0;
    *(float4*)&Bs[bk][bc + 64] = b1;
    __syncthreads();
    #pragma unroll
    for (int kk = 0; kk < 16; kk++) {
      const float4 A0 = *(const float4*)&As[kk][8 * ty];
      const float4 A1 = *(const float4*)&As[kk][8 * ty + 4];
      const float4 B0 = *(const float4*)&Bs[kk][8 * tx];
      const float4 B1 = *(const float4*)&Bs[kk][8 * tx + 4];
      const float a[8]  = {A0.x, A0.y, A0.z, A0.w, A1.x, A1.y, A1.z, A1.w};
      const float bb[8] = {B0.x, B0.y, B0.z, B0.w, B1.x, B1.y, B1.z, B1.w};
      #pragma unroll
      for (int i = 0; i < 8; i++)
        #pragma unroll
        for (int j = 0; j < 8; j++)
          acc[i][j] = fmaf(a[i], bb[j], acc[i][j]);
    }
    __syncthreads();
  }

  if (z == 2) {
    // scatter V transposed as bf16: Vt[(b*NH+h)*DH + d][s]
    #pragma unroll
    for (int i = 0; i < 8; i++) {
      const int grow = row0 + 8 * ty + i;
      const int b = grow >> 11, ss = grow & (SEQ - 1);
      #pragma unroll
      for (int j = 0; j < 8; j++) {
        const int col = col0 + 8 * tx + j;
        const int hh = col >> 6, dd = col & (DH - 1);
        Vt[(size_t)((b * NH + hh) * DH + dd) * SEQ + ss] = f2bf(acc[i][j]);
      }
    }
  } else {
    #pragma unroll
    for (int i = 0; i < 8; i++) {
      const int grow = row0 + 8 * ty + i;
      float4 v0 = make_float4(acc[i][0], acc[i][1], acc[i][2], acc[i][3]);
      float4 v1 = make_float4(acc[i][4], acc[i][5], acc[i][6], acc[i][7]);
      *(float4*)&C[grow * DM + col0 + 8 * tx]     = v0;
      *(float4*)&C[grow * DM + col0 + 8 * tx + 4] = v1;
    }
  }
}

// ---------------------------------------------------------------------------
// RoPE + hi/lo bf16 split. y==0: Q (scaled by 1/32) -> Qh,Ql. y==1: K -> Kh,Kl.
// ---------------------------------------------------------------------------
__global__ __launch_bounds__(256)
void rope_split(const float* __restrict__ Q, const float* __restrict__ K,
                unsigned short* __restrict__ Qh, unsigned short* __restrict__ Ql,
                unsigned short* __restrict__ Kh, unsigned short* __restrict__ Kl)
{
  const int idx = blockIdx.x * 256 + threadIdx.x;   // 0..524287
  const int row = idx >> 7;
  const int d0  = (idx & 127) << 3;
  const bool isK = (blockIdx.y != 0);
  const float* __restrict__ src = isK ? K : Q;

  float4 v0 = *(const float4*)&src[(size_t)row * DM + d0];
  float4 v1 = *(const float4*)&src[(size_t)row * DM + d0 + 4];
  float vals[8] = {v0.x, v0.y, v0.z, v0.w, v1.x, v1.y, v1.z, v1.w};

  const float s = (float)(row & (SEQ - 1));
  const int p0 = (d0 & (DH - 1)) >> 1;
  float outv[8];
  #pragma unroll
  for (int i = 0; i < 4; i++) {
    const float fr = exp2f((float)(p0 + i) * -0.41524101186092030f);
    float sn, cs;
    sincosf(s * fr, &sn, &cs);
    const float e = vals[2 * i], o = vals[2 * i + 1];
    outv[2 * i]     = e * cs - o * sn;
    outv[2 * i + 1] = e * sn + o * cs;
  }

  const float scale = isK ? 1.0f : 0.03125f;   // fold 1/sqrt(1024) into Q
  unsigned short* __restrict__ Hp = isK ? Kh : Qh;
  unsigned short* __restrict__ Lp = isK ? Kl : Ql;
  short8v hv, lv;
  #pragma unroll
  for (int e = 0; e < 8; e++) {
    const float x = outv[e] * scale;
    const unsigned short hb = f2bf(x);
    hv[e] = (short)hb;
    lv[e] = (short)f2bf(x - bf2f(hb));
  }
  *(short8v*)&Hp[(size_t)row * DM + d0] = hv;
  *(short8v*)&Lp[(size_t)row * DM + d0] = lv;
}

// ---------------------------------------------------------------------------
// MFMA flash attention. Block = 64 q rows (4 waves x 16), K/V tiles of 64.
// QK^T split-bf16 (3 MFMAs), PV plain bf16. Online softmax in fp32.
// ---------------------------------------------------------------------------
__global__ __launch_bounds__(256)
void attn_mfma(const unsigned short* __restrict__ Qh, const unsigned short* __restrict__ Ql,
               const unsigned short* __restrict__ Kh, const unsigned short* __restrict__ Kl,
               const unsigned short* __restrict__ Vt, float* __restrict__ A)
{
  __shared__ __align__(16) unsigned short Khl[2][2][64][32]; // [hi/lo][dblk][krow][d] 16KB
  __shared__ __align__(16) unsigned short Vtl[64][72];       // [d][k] padded        9.2KB
  __shared__ __align__(16) unsigned short Pl[4][16][72];     // per-wave P           9.2KB

  const int t = threadIdx.x;
  const int lane = t & 63, w = t >> 6;
  const int l4 = lane & 15, lh = lane >> 4;
  const int qblk = blockIdx.x, bh = blockIdx.y;
  const int b = bh >> 4, h = bh & 15;
  const int q0w = qblk * 64 + w * 16;

  // Q fragments (A-operand): row = lane&15, k = (lane>>4)*8 + e
  short8v aq[2][2];
  {
    const size_t qoff = (size_t)((b * SEQ) + (q0w + l4)) * DM + h * DH;
    #pragma unroll
    for (int db = 0; db < 2; db++) {
      aq[0][db] = *(const short8v*)&Qh[qoff + db * 32 + lh * 8];
      aq[1][db] = *(const short8v*)&Ql[qoff + db * 32 + lh * 8];
    }
  }

  f32x4 o[4];
  float m[4], ls[4];
  #pragma unroll
  for (int j = 0; j < 4; j++) {
    o[j] = (f32x4){0.f, 0.f, 0.f, 0.f};
    m[j] = -1e30f; ls[j] = 0.f;
  }

  const unsigned short* __restrict__ Vg = Vt + (size_t)bh * DH * SEQ;
  const int nt = qblk + 1;

  for (int kt = 0; kt < nt; kt++) {
    // ---- stage K tile (hi/lo) and V tile
    {
      const int kr = t >> 2, kc = t & 3;
      const size_t koff = (size_t)(b * SEQ + kt * 64 + kr) * DM + h * DH;
      #pragma unroll
      for (int db = 0; db < 2; db++) {
        short8v vh = *(const short8v*)&Kh[koff + db * 32 + kc * 8];
        short8v vl = *(const short8v*)&Kl[koff + db * 32 + kc * 8];
        *(short8v*)&Khl[0][db][kr][kc * 8] = vh;
        *(short8v*)&Khl[1][db][kr][kc * 8] = vl;
      }
      // V tile: 64 d-rows x 64 k — each thread loads TWO 8-elem chunks
      // (k = kc*8 and kc*8+32) so the full k range 0..63 is covered.
      short8v vv0 = *(const short8v*)&Vg[(size_t)kr * SEQ + kt * 64 + kc * 8];
      short8v vv1 = *(const short8v*)&Vg[(size_t)kr * SEQ + kt * 64 + kc * 8 + 32];
      *(short8v*)&Vtl[kr][kc * 8]      = vv0;
      *(short8v*)&Vtl[kr][kc * 8 + 32] = vv1;
    }
    __syncthreads();

    // ---- S = Q K^T  (split bf16: hi*hi + hi*lo + lo*hi)
    f32x4 s[4];
    #pragma unroll
    for (int n = 0; n < 4; n++) s[n] = (f32x4){0.f, 0.f, 0.f, 0.f};
    #pragma unroll
    for (int n = 0; n < 4; n++) {
      const int krow = n * 16 + l4;
      #pragma unroll
      for (int db = 0; db < 2; db++) {
        short8v bhv = *(const short8v*)&Khl[0][db][krow][lh * 8];
        short8v blv = *(const short8v*)&Khl[1][db][krow][lh * 8];
        s[n] = __builtin_amdgcn_mfma_f32_16x16x32_bf16(aq[0][db], bhv, s[n], 0, 0, 0);
        s[n] = __builtin_amdgcn_mfma_f32_16x16x32_bf16(aq[0][db], blv, s[n], 0, 0, 0);
        s[n] = __builtin_amdgcn_mfma_f32_16x16x32_bf16(aq[1][db], bhv, s[n], 0, 0, 0);
      }
    }

    // ---- causal mask + online softmax (row = lh*4 + j, col = n*16 + l4)
    const int kb = kt * 64;
    #pragma unroll
    for (int j = 0; j < 4; j++) {
      const int qg = q0w + lh * 4 + j;
      #pragma unroll
      for (int n = 0; n < 4; n++)
        if (kb + n * 16 + l4 > qg) s[n][j] = -1e30f;

      float v = fmaxf(fmaxf(s[0][j], s[1][j]), fmaxf(s[2][j], s[3][j]));
      #pragma unroll
      for (int off = 1; off < 16; off <<= 1) v = fmaxf(v, __shfl_xor(v, off));
      const float nm = fmaxf(m[j], v);
      const float corr = __expf(m[j] - nm);
      m[j] = nm;
      float rs = 0.f;
      #pragma unroll
      for (int n = 0; n < 4; n++) {
        const float p = __expf(s[n][j] - nm);
        s[n][j] = p;
        rs += p;
      }
      #pragma unroll
      for (int off = 1; off < 16; off <<= 1) rs += __shfl_xor(rs, off);
      ls[j] = ls[j] * corr + rs;
      #pragma unroll
      for (int df = 0; df < 4; df++) o[df][j] *= corr;
    }

    // ---- P -> LDS (bf16, C-layout -> A-layout redistribution)
    #pragma unroll
    for (int n = 0; n < 4; n++)
      #pragma unroll
      for (int j = 0; j < 4; j++)
        Pl[w][lh * 4 + j][n * 16 + l4] = f2bf(s[n][j]);

    // ---- O += P V
    #pragma unroll
    for (int kb2 = 0; kb2 < 2; kb2++) {
      short8v ap = *(const short8v*)&Pl[w][l4][kb2 * 32 + lh * 8];
      #pragma unroll
      for (int df = 0; df < 4; df++) {
        short8v bv = *(const short8v*)&Vtl[df * 16 + l4][kb2 * 32 + lh * 8];
        o[df] = __builtin_amdgcn_mfma_f32_16x16x32_bf16(ap, bv, o[df], 0, 0, 0);
      }
    }
    __syncthreads();
  }

  // ---- write A (fp32)
  #pragma unroll
  for (int j = 0; j < 4; j++) {
    const float inv = 1.0f / ls[j];
    const size_t row = (size_t)(b * SEQ + q0w + lh * 4 + j);
    #pragma unroll
    for (int df = 0; df < 4; df++)
      A[row * DM + h * DH + df * 16 + l4] = o[df][j] * inv;
  }
}

// ---------------------------------------------------------------------------
extern "C" void kernel_launch(void* const* d_in, const int* in_sizes, int n_in,
                              void* d_out, int out_size, void* d_ws, size_t ws_size,
                              hipStream_t stream) {
  const float* x  = (const float*)d_in[0];
  const float* qw = (const float*)d_in[1];
  const float* kw = (const float*)d_in[2];
  const float* vw = (const float*)d_in[3];
  const float* ow = (const float*)d_in[4];
  float* out = (float*)d_out;

  char* ws = (char*)d_ws;
  float* Q = (float*)ws;                                   // 16 MB
  float* K = (float*)(ws + (16u << 20));                   // 16 MB
  unsigned short* Kh = (unsigned short*)(ws + (32u << 20)); // 8 MB
  unsigned short* Kl = (unsigned short*)(ws + (40u << 20)); // 8 MB
  unsigned short* Vt = (unsigned short*)(ws + (48u << 20)); // 8 MB
  float* A = Q;                                            // Q dead after rope_split
  unsigned short* Qh = (unsigned short*)d_out;             // 8 MB (d_out scratch)
  unsigned short* Ql = Qh + (size_t)BS_ROWS * DM;          // 8 MB

  dim3 blk(256);
  // QKV projections (V -> transposed bf16)
  gemm_k<<<dim3(DM / 128, BS_ROWS / 128, 3), blk, 0, stream>>>(
      x, qw, kw, vw, Q, K, Vt);
  // RoPE + split
  rope_split<<<dim3(2048, 2), blk, 0, stream>>>(Q, K, Qh, Ql, Kh, Kl);
  // attention
  attn_mfma<<<dim3(SEQ / 64, BATCH * NH), blk, 0, stream>>>(Qh, Ql, Kh, Kl, Vt, A);
  // output projection (z grid of 1 -> uses W0/C0)
  gemm_k<<<dim3(DM / 128, BS_ROWS / 128, 1), blk, 0, stream>>>(
      A, ow, ow, ow, out, out, (unsigned short*)Vt);
}